// Round 15
// baseline (724.949 us; speedup 1.0000x reference)
//
#include <hip/hip_runtime.h>
#include <math.h>

typedef __bf16 bf16;
typedef __bf16 bf16x8 __attribute__((ext_vector_type(8)));
typedef __bf16 bf16x4 __attribute__((ext_vector_type(4)));
typedef __bf16 bf16x2 __attribute__((ext_vector_type(2)));
typedef float f32x4 __attribute__((ext_vector_type(4)));

#define ROWS 16384   // B*T

// ---- direct global->LDS 16B DMA (gfx950). LDS dest = wave-uniform base + lane*16.
typedef __attribute__((address_space(3))) void* lds_vp;
typedef const __attribute__((address_space(1))) void* glb_vp;
__device__ __forceinline__ void gload16(const void* g, void* l) {
  __builtin_amdgcn_global_load_lds((glb_vp)g, (lds_vp)l, 16, 0, 0);
}

// ---------------- 0. cast f32 -> bf16, all four weights in one launch --------
__global__ __launch_bounds__(256) void cast4_kernel(
    const float* __restrict__ s0, bf16* __restrict__ d0, int n0,
    const float* __restrict__ s1, bf16* __restrict__ d1, int n1,
    const float* __restrict__ s2, bf16* __restrict__ d2, int n2,
    const float* __restrict__ s3, bf16* __restrict__ d3, int n3)
{
  int i = (blockIdx.x * 256 + threadIdx.x) * 8;
  const float* s; bf16* d;
  if (i < n0)                { s = s0; d = d0; }
  else if ((i -= n0) < n1)   { s = s1; d = d1; }
  else if ((i -= n1) < n2)   { s = s2; d = d2; }
  else if ((i -= n2) < n3)   { s = s3; d = d3; }
  else return;
  float4 a = *(const float4*)(s + i);
  float4 b = *(const float4*)(s + i + 4);
  bf16x8 o;
  o[0] = (bf16)a.x; o[1] = (bf16)a.y; o[2] = (bf16)a.z; o[3] = (bf16)a.w;
  o[4] = (bf16)b.x; o[5] = (bf16)b.y; o[6] = (bf16)b.z; o[7] = (bf16)b.w;
  *(bf16x8*)(d + i) = o;
}

// ---------------- 1. x = frame_features + sinusoidal PE ----------------
__global__ __launch_bounds__(256) void pe_add_kernel(
    const float* __restrict__ ff, const int* __restrict__ idx, bf16* __restrict__ x)
{
  int p   = blockIdx.x * 256 + threadIdx.x;   // over ROWS*512 sin/cos pairs
  int row = p >> 9;
  int j   = p & 511;
  float pos = (float)idx[row];
  float d2  = (float)(2 * j) * (1.0f / 1024.0f);
  float dv  = expf(-9.210340371976184f * d2);   // 10000^(-2j/D)
  float ang = pos * dv;
  float s, c;
  sincosf(ang, &s, &c);
  int base = row * 1024 + 2 * j;
  float2 f = *(const float2*)(ff + base);
  bf16x2 o;
  o[0] = (bf16)(f.x + s);
  o[1] = (bf16)(f.y + c);
  *(bf16x2*)(x + base) = o;
}

// ---------------- 2. 128x128 GEMM, BK=32 x 2 bufs (32 KB), 256 thr ----------
// r15: occupancy fix. r14 proved residency is REGISTER-capped (232 regs/thread
// = 8 waves/CU = 1 block, any LDS size). Halve the accumulator: 4 waves (2x2),
// per-wave 64x64 (acc[4][4]=64 regs) -> ~121 regs/thread -> 4 blocks/CU
// (LDS 32KB allows 5). Same one-region-per-kt schedule as r8/r10:
// {stage kt m+1 -> buf b^1 (4 gload16/thread); 8 C++ ds_reads; 16 MFMA;
// vmcnt(0); barrier}. Cross-block wave overlap (m97/m114 regime) now covers
// the per-kt drain. Swizzle involution unchanged (subtile-internal).
#define MFMA16 __builtin_amdgcn_mfma_f32_16x16x32_bf16

template<bool GELU, bool RES>
__global__ __launch_bounds__(256, 4) void gemm8(
    const bf16* __restrict__ A, const bf16* __restrict__ Bw,
    const float* __restrict__ bias, const bf16* __restrict__ resid,
    bf16* __restrict__ C, int M, int N, int K)
{
  extern __shared__ char smem[];       // 32768 B: 2 x (A 8KB | B 8KB)

  const int tid  = threadIdx.x;
  const int wave = tid >> 6;
  const int lane = tid & 63;
  const int wm = wave >> 1, wn = wave & 1;   // 2 x 2 wave grid, 64x64 each
  const int ln = lane & 15, q = lane >> 4;

  // XCD-aware block swizzle, bn-fastest within each XCD chunk
  const int nwg = gridDim.x;
  const int nbn = N >> 7;
  const int swz = (blockIdx.x & 7) * (nwg >> 3) + (blockIdx.x >> 3);
  const int bm = (swz / nbn) << 7;
  const int bn = (swz % nbn) << 7;

  // LDS read bases (elem units). buf b at b*8192 elems; B half at +4096.
  const bf16* lA = (const bf16*)smem;
  const int rsw = (ln * 32 + q * 8) ^ (((ln >> 3) & 1) << 4);
  const int raw = wm * 2048 + rsw;           // + b*8192 + t*512
  const int rbw = 4096 + wn * 2048 + rsw;    // + b*8192 + n*512

  // staging source (pre-swizzled lane; involution matches read-side XOR)
  const int le = lane ^ (((lane >> 5) & 1) << 1);
  const int sr = le >> 2;              // row within 16-row group
  const int sc = (le & 3) * 8;         // k-col within 32-col subtile
  const bf16* gAw = A  + (size_t)(bm + wave * 32 + sr) * K + sc;
  const bf16* gBw = Bw + (size_t)(bn + wave * 32 + sr) * K + sc;

#define STAGE_A(BB, KOFF) do { \
    char* _d = smem + (BB) * 16384 + wave * 2048; \
    gload16(gAw + (KOFF), _d); \
    gload16(gAw + 16 * (size_t)K + (KOFF), _d + 1024); } while (0)
#define STAGE_B(BB, KOFF) do { \
    char* _d = smem + (BB) * 16384 + 8192 + wave * 2048; \
    gload16(gBw + (KOFF), _d); \
    gload16(gBw + 16 * (size_t)K + (KOFF), _d + 1024); } while (0)

  f32x4 acc[4][4];
#pragma unroll
  for (int i = 0; i < 4; i++)
#pragma unroll
    for (int j = 0; j < 4; j++) acc[i][j] = {0.f, 0.f, 0.f, 0.f};

  // bias prefetch (held in 4 VGPRs through the loop)
  float bv[4];
#pragma unroll
  for (int tn = 0; tn < 4; tn++) bv[tn] = bias[bn + wn * 64 + tn * 16 + ln];

  const int nkt = K >> 5;              // 32 (K=1024) or 128 (K=4096); even

  // ---- prologue: stage kt0 -> buf0, confirm
  STAGE_A(0, 0);  STAGE_B(0, 0);
  asm volatile("s_waitcnt vmcnt(0)");
  __builtin_amdgcn_s_barrier();

#define MFROW(T, AF) \
    acc[T][0] = MFMA16(AF, bq0, acc[T][0], 0, 0, 0); \
    acc[T][1] = MFMA16(AF, bq1, acc[T][1], 0, 0, 0); \
    acc[T][2] = MFMA16(AF, bq2, acc[T][2], 0, 0, 0); \
    acc[T][3] = MFMA16(AF, bq3, acc[T][3], 0, 0, 0);

  // One K-tile: single scheduling region; NEXT = kt index staged into buf^1.
#define KT(B_, NEXT) { \
    const bool stg = (NEXT) < nkt; \
    if (stg) { STAGE_A((B_) ^ 1, (NEXT) * 32); STAGE_B((B_) ^ 1, (NEXT) * 32); } \
    const bf16* _pa = lA + (B_) * 8192 + raw; \
    const bf16* _pb = lA + (B_) * 8192 + rbw; \
    bf16x8 af0 = *(const bf16x8*)(_pa); \
    bf16x8 af1 = *(const bf16x8*)(_pa + 512); \
    bf16x8 af2 = *(const bf16x8*)(_pa + 1024); \
    bf16x8 af3 = *(const bf16x8*)(_pa + 1536); \
    bf16x8 bq0 = *(const bf16x8*)(_pb); \
    bf16x8 bq1 = *(const bf16x8*)(_pb + 512); \
    bf16x8 bq2 = *(const bf16x8*)(_pb + 1024); \
    bf16x8 bq3 = *(const bf16x8*)(_pb + 1536); \
    __builtin_amdgcn_s_setprio(1); \
    MFROW(0, af0) MFROW(1, af1) MFROW(2, af2) MFROW(3, af3) \
    __builtin_amdgcn_s_setprio(0); \
    if (stg) { asm volatile("s_waitcnt vmcnt(0)"); } \
    __builtin_amdgcn_s_barrier(); }

  // ---- main loop: unrolled x2 so buf indices are literal
  for (int m = 0; m < nkt; m += 2) {
    KT(0, m + 1)
    KT(1, m + 2)
  }
#undef KT
#undef MFROW
#undef STAGE_A
#undef STAGE_B

  // ---- epilogue: 4 passes over tm. C/D layout col=ln, row=q*4+reg.
  // LDS repack 32x128 (stride 136: 2-way banks), coalesced read-back.
  bf16* eb = (bf16*)smem;
  const int lrow = tid >> 3;          // 0..31
  const int cb   = (tid & 7) * 16;    // 0..112
#pragma unroll
  for (int tm = 0; tm < 4; tm++) {
    __syncthreads();
#pragma unroll
    for (int tn = 0; tn < 4; tn++)
#pragma unroll
      for (int i = 0; i < 4; i++)
        eb[(wm * 16 + q * 4 + i) * 136 + wn * 64 + tn * 16 + ln] =
            (bf16)(acc[tm][tn][i] + bv[tn]);
    __syncthreads();
    int gR = bm + (lrow >> 4) * 64 + tm * 16 + (lrow & 15);
    size_t rowoff = (size_t)gR * N + bn + cb;
    bf16x8 v0 = *(const bf16x8*)&eb[lrow * 136 + cb];
    bf16x8 v1 = *(const bf16x8*)&eb[lrow * 136 + cb + 8];
    if (RES) {
      bf16x8 r0 = *(const bf16x8*)(resid + rowoff);
      bf16x8 r1 = *(const bf16x8*)(resid + rowoff + 8);
#pragma unroll
      for (int u = 0; u < 8; u++) {
        v0[u] = (bf16)((float)v0[u] + (float)r0[u]);
        v1[u] = (bf16)((float)v1[u] + (float)r1[u]);
      }
    }
    if (GELU) {
      // tanh-form GELU, NaN-safe: a - a/(1+exp2(2.3022082*a*(1+0.044715a^2)))
#pragma unroll
      for (int u = 0; u < 8; u++) {
        float a = (float)v0[u], c = (float)v1[u];
        float ea = __builtin_amdgcn_exp2f(2.3022082f * a * (1.0f + 0.044715f * a * a));
        float ec = __builtin_amdgcn_exp2f(2.3022082f * c * (1.0f + 0.044715f * c * c));
        v0[u] = (bf16)(a - a * __builtin_amdgcn_rcpf(ea + 1.0f));
        v1[u] = (bf16)(c - c * __builtin_amdgcn_rcpf(ec + 1.0f));
      }
    }
    *(bf16x8*)(C + rowoff)     = v0;
    *(bf16x8*)(C + rowoff + 8) = v1;
  }
}

// ---------------- 3. windowed attention: bf16 LDS, b128 reads ----------------
__global__ __launch_bounds__(256) void attn_kernel(
    const bf16* __restrict__ qkv, bf16* __restrict__ o)
{
  __shared__ bf16 sq[16][136], sk[16][136], sv[16][136];  // pad 8 elems = 16 B
  __shared__ float ss[16][17];

  int wid = blockIdx.x;
  int h   = wid & 7;
  int win = wid >> 3;
  int tb  = win * 16;     // token base row

  int t  = threadIdx.x;
  int r  = t >> 4;        // 0..15
  int c8 = (t & 15) * 8;  // 0..120

  const bf16* base = qkv + (size_t)(tb + r) * 3072 + c8;
  *(bf16x8*)&sq[r][c8] = *(const bf16x8*)(base + h * 128);
  *(bf16x8*)&sk[r][c8] = *(const bf16x8*)(base + 1024 + h * 128);
  *(bf16x8*)&sv[r][c8] = *(const bf16x8*)(base + 2048 + h * 128);
  __syncthreads();

  {  // scores: thread (i,j) does 128-dot via 16x2 b128 reads
    int i = t >> 4, jj = t & 15;
    float s = 0.f;
#pragma unroll
    for (int d8 = 0; d8 < 16; d8++) {
      bf16x8 qa = *(const bf16x8*)&sq[i][d8 * 8];
      bf16x8 kb = *(const bf16x8*)&sk[jj][d8 * 8];
#pragma unroll
      for (int u = 0; u < 8; u++) s += (float)qa[u] * (float)kb[u];
    }
    ss[i][jj] = s * 0.08838834764831845f;   // 1/sqrt(128)
  }
  __syncthreads();

  if (t < 16) {  // softmax, one thread per row
    float m = -1e30f;
    for (int jj = 0; jj < 16; jj++) m = fmaxf(m, ss[t][jj]);
    float sum = 0.f;
    for (int jj = 0; jj < 16; jj++) { float e = expf(ss[t][jj] - m); ss[t][jj] = e; sum += e; }
    float inv = 1.0f / sum;
    for (int jj = 0; jj < 16; jj++) ss[t][jj] *= inv;
  }
  __syncthreads();

  {  // o = attn @ v : thread does 8 output elems; 16 b128 reads
    int i = t >> 4; int d0 = (t & 15) * 8;
    float acc[8] = {0, 0, 0, 0, 0, 0, 0, 0};
#pragma unroll
    for (int jj = 0; jj < 16; jj++) {
      float a = ss[i][jj];
      bf16x8 vv8 = *(const bf16x8*)&sv[jj][d0];
#pragma unroll
      for (int u = 0; u < 8; u++) acc[u] += a * (float)vv8[u];
    }
    bf16* op = o + (size_t)(tb + i) * 1024 + h * 128 + d0;
    bf16x8 ov;
#pragma unroll
    for (int u = 0; u < 8; u++) ov[u] = (bf16)acc[u];
    *(bf16x8*)op = ov;
  }
}

// ---------------- 4. LayerNorm (row = 1024, biased var), templated output ------
template<typename OUT_T>
__global__ __launch_bounds__(256) void ln_kernel(
    const bf16* __restrict__ x, const float* __restrict__ g,
    const float* __restrict__ b, OUT_T* __restrict__ y)
{
  __shared__ float red[8];
  int row = blockIdx.x;
  int t   = threadIdx.x;
  int lane = t & 63, wave = t >> 6;

  bf16x4 v4 = *(const bf16x4*)(x + (size_t)row * 1024 + t * 4);
  float v[4];
  float s = 0.f, sq = 0.f;
#pragma unroll
  for (int u = 0; u < 4; u++) {
    v[u] = (float)v4[u];
    s += v[u];
    sq += v[u] * v[u];
  }
  for (int off = 32; off > 0; off >>= 1) {
    s  += __shfl_down(s, off);
    sq += __shfl_down(sq, off);
  }
  if (lane == 0) { red[wave * 2] = s; red[wave * 2 + 1] = sq; }
  __syncthreads();
  float st = red[0] + red[2] + red[4] + red[6];
  float qt = red[1] + red[3] + red[5] + red[7];
  float mean = st * (1.0f / 1024.0f);
  float var  = qt * (1.0f / 1024.0f) - mean * mean;
  float inv  = rsqrtf(var + 1e-5f);
  int c = t * 4;
  OUT_T* yr = y + (size_t)row * 1024 + c;
#pragma unroll
  for (int u = 0; u < 4; u++)
    yr[u] = (OUT_T)((v[u] - mean) * inv * g[c + u] + b[c + u]);
}

// ---------------- launch ----------------
extern "C" void kernel_launch(void* const* d_in, const int* in_sizes, int n_in,
                              void* d_out, int out_size, void* d_ws, size_t ws_size,
                              hipStream_t stream) {
  const float* ff    = (const float*)d_in[0];
  const int*   idx   = (const int*)d_in[1];
  const float* w_qkv = (const float*)d_in[2];
  const float* b_qkv = (const float*)d_in[3];
  const float* w_out = (const float*)d_in[4];
  const float* b_out = (const float*)d_in[5];
  const float* w1    = (const float*)d_in[6];
  const float* b1    = (const float*)d_in[7];
  const float* w2    = (const float*)d_in[8];
  const float* b2    = (const float*)d_in[9];
  const float* g1    = (const float*)d_in[10];
  const float* be1   = (const float*)d_in[11];
  const float* g2    = (const float*)d_in[12];
  const float* be2   = (const float*)d_in[13];
  float* out = (float*)d_out;

  char* p = (char*)d_ws;
  bf16* x_bf = (bf16*)p;  p += (size_t)ROWS * 1024 * 2;   // 32MB
  bf16* big  = (bf16*)p;  p += (size_t)ROWS * 4096 * 2;   // 128MB: qkv|o, later gelu acts
  bf16* s_bf = (bf16*)p;  p += (size_t)ROWS * 1024 * 2;   // 32MB
  bf16* h_bf = (bf16*)p;  p += (size_t)ROWS * 1024 * 2;   // 32MB
  bf16* wqb  = (bf16*)p;  p += (size_t)3072 * 1024 * 2;
  bf16* wob  = (bf16*)p;  p += (size_t)1024 * 1024 * 2;
  bf16* w1b  = (bf16*)p;  p += (size_t)4096 * 1024 * 2;
  bf16* w2b  = (bf16*)p;  p += (size_t)1024 * 4096 * 2;
  bf16* o_bf = big + (size_t)ROWS * 3072;   // lives in big's tail during attention
  bf16* g_bf = big;                          // reuses big after attention done

  // all four weight casts in one launch (12.58M elems / 8 / 256 = 6144 blocks)
  cast4_kernel<<<6144, 256, 0, stream>>>(
      w_qkv, wqb, 3072 * 1024,
      w_out, wob, 1024 * 1024,
      w1,    w1b, 4096 * 1024,
      w2,    w2b, 1024 * 4096);

  pe_add_kernel<<<ROWS * 512 / 256, 256, 0, stream>>>(ff, idx, x_bf);

  // grids: (M/128) * (N/128); all % 8 == 0 for the XCD swizzle. 32 KB LDS.
  gemm8<false, false><<<128 * 24, 256, 32768, stream>>>(
      x_bf, wqb, b_qkv, nullptr, big, ROWS, 3072, 1024);
  attn_kernel<<<(ROWS / 16) * 8, 256, 0, stream>>>(big, o_bf);
  gemm8<false, true><<<128 * 8, 256, 32768, stream>>>(
      o_bf, wob, b_out, x_bf, s_bf, ROWS, 1024, 1024);
  ln_kernel<bf16><<<ROWS, 256, 0, stream>>>(s_bf, g1, be1, h_bf);
  gemm8<true, false><<<128 * 32, 256, 32768, stream>>>(
      h_bf, w1b, b1, nullptr, big, ROWS, 4096, 1024);
  gemm8<false, true><<<128 * 8, 256, 32768, stream>>>(
      g_bf, w2b, b2, h_bf, s_bf, ROWS, 1024, 4096);
  ln_kernel<float><<<ROWS, 256, 0, stream>>>(s_bf, g2, be2, out);
}

// Round 16
// 641.060 us; speedup vs baseline: 1.1309x; 1.1309x over previous
//
#include <hip/hip_runtime.h>
#include <math.h>

typedef __bf16 bf16;
typedef __bf16 bf16x8 __attribute__((ext_vector_type(8)));
typedef __bf16 bf16x4 __attribute__((ext_vector_type(4)));
typedef __bf16 bf16x2 __attribute__((ext_vector_type(2)));
typedef float f32x4 __attribute__((ext_vector_type(4)));

#define ROWS 16384   // B*T

// ---- direct global->LDS 16B DMA (gfx950). LDS dest = wave-uniform base + lane*16.
typedef __attribute__((address_space(3))) void* lds_vp;
typedef const __attribute__((address_space(1))) void* glb_vp;
__device__ __forceinline__ void gload16(const void* g, void* l) {
  __builtin_amdgcn_global_load_lds((glb_vp)g, (lds_vp)l, 16, 0, 0);
}

// ---------------- 0. cast f32 -> bf16, all four weights in one launch --------
__global__ __launch_bounds__(256) void cast4_kernel(
    const float* __restrict__ s0, bf16* __restrict__ d0, int n0,
    const float* __restrict__ s1, bf16* __restrict__ d1, int n1,
    const float* __restrict__ s2, bf16* __restrict__ d2, int n2,
    const float* __restrict__ s3, bf16* __restrict__ d3, int n3)
{
  int i = (blockIdx.x * 256 + threadIdx.x) * 8;
  const float* s; bf16* d;
  if (i < n0)                { s = s0; d = d0; }
  else if ((i -= n0) < n1)   { s = s1; d = d1; }
  else if ((i -= n1) < n2)   { s = s2; d = d2; }
  else if ((i -= n2) < n3)   { s = s3; d = d3; }
  else return;
  float4 a = *(const float4*)(s + i);
  float4 b = *(const float4*)(s + i + 4);
  bf16x8 o;
  o[0] = (bf16)a.x; o[1] = (bf16)a.y; o[2] = (bf16)a.z; o[3] = (bf16)a.w;
  o[4] = (bf16)b.x; o[5] = (bf16)b.y; o[6] = (bf16)b.z; o[7] = (bf16)b.w;
  *(bf16x8*)(d + i) = o;
}

// ---------------- 1. x = frame_features + sinusoidal PE (hw trig) ------------
// r16: libm expf/sincosf (~40 VALU ops, divergent range reduction) ->
// hw exp2 + fract + v_sin/v_cos (revolutions). Error ~3e-3 << 0.0625 tol.
__global__ __launch_bounds__(256) void pe_add_kernel(
    const float* __restrict__ ff, const int* __restrict__ idx, bf16* __restrict__ x)
{
  int p   = blockIdx.x * 256 + threadIdx.x;   // over ROWS*512 sin/cos pairs
  int row = p >> 9;
  int j   = p & 511;
  float pos = (float)idx[row];
  float d2  = (float)(2 * j) * (1.0f / 1024.0f);
  // 10000^(-d2) = exp2(-log2(10000)*d2); log2(10000)=13.287712379549449
  float dv  = __builtin_amdgcn_exp2f(-13.287712379549449f * d2);
  float ang = pos * dv;
  float rev = ang * 0.15915494309189535f;     // /2pi
  rev = rev - floorf(rev);                     // v_fract
  float s = __builtin_amdgcn_sinf(rev);        // sin(rev*2pi)
  float c = __builtin_amdgcn_cosf(rev);        // cos(rev*2pi)
  int base = row * 1024 + 2 * j;
  float2 f = *(const float2*)(ff + base);
  bf16x2 o;
  o[0] = (bf16)(f.x + s);
  o[1] = (bf16)(f.y + c);
  *(bf16x2*)(x + base) = o;
}

// ---------------- 2. 256x256 GEMM, BK=32 x 4 bufs, ONE region per K-tile ----
// REVERTED to the r8 core exactly (twice-measured best: 158.3/159.1 us FFN1,
// MfmaUtil 37.8/37.9, conflicts 0, FETCH 148 MB). r15 proved the 34-38%
// plateau is the LDS fragment-read bandwidth cap of this fragment scheme
// (384 B/MFMA vs ~1.2 cyc/MFMA CU issue), NOT schedule/occupancy — so this
// core is frozen; no further schedule experiments.
#define MFMA16 __builtin_amdgcn_mfma_f32_16x16x32_bf16

template<bool GELU, bool RES>
__global__ __launch_bounds__(512, 2) void gemm8(
    const bf16* __restrict__ A, const bf16* __restrict__ Bw,
    const float* __restrict__ bias, const bf16* __restrict__ resid,
    bf16* __restrict__ C, int M, int N, int K)
{
  extern __shared__ char smem[];       // 131072 B: 4 x (A 16KB | B 16KB)

  const int tid  = threadIdx.x;
  const int wave = tid >> 6;
  const int lane = tid & 63;
  const int wm = wave >> 2, wn = wave & 3;   // 2 x 4 wave grid
  const int ln = lane & 15, q = lane >> 4;
  const int wm8 = wm * 8, wn4 = wn * 4;

  // XCD-aware block swizzle, bn-fastest within each XCD chunk
  const int nwg = gridDim.x;
  const int nbn = N >> 8;
  const int swz = (blockIdx.x & 7) * (nwg >> 3) + (blockIdx.x >> 3);
  const int bm = (swz / nbn) << 8;
  const int bn = (swz % nbn) << 8;

  // LDS read bases (elem units). buf b at b*16384 elems; B half at +8192.
  const bf16* lA = (const bf16*)smem;
  const int rsw = (ln * 32 + q * 8) ^ (((ln >> 3) & 1) << 4);
  const int raw = wm8 * 512 + rsw;            // + b*16384 + t*512
  const int rbw = 8192 + wn4 * 512 + rsw;     // + b*16384 + n*512

  // staging source (pre-swizzled lane; involution matches read-side XOR)
  const int le = lane ^ (((lane >> 5) & 1) << 1);
  const int sr = le >> 2;              // row within 16-row group
  const int sc = (le & 3) * 8;         // k-col within 32-col subtile
  const bf16* gAw = A  + (size_t)(bm + wave * 32 + sr) * K + sc;
  const bf16* gBw = Bw + (size_t)(bn + wave * 32 + sr) * K + sc;

#define STAGE_A(BB, KOFF) do { \
    char* _d = smem + (BB) * 32768 + wave * 2048; \
    gload16(gAw + (KOFF), _d); \
    gload16(gAw + 16 * (size_t)K + (KOFF), _d + 1024); } while (0)
#define STAGE_B(BB, KOFF) do { \
    char* _d = smem + (BB) * 32768 + 16384 + wave * 2048; \
    gload16(gBw + (KOFF), _d); \
    gload16(gBw + 16 * (size_t)K + (KOFF), _d + 1024); } while (0)

  f32x4 acc[8][4];
#pragma unroll
  for (int i = 0; i < 8; i++)
#pragma unroll
    for (int j = 0; j < 4; j++) acc[i][j] = {0.f, 0.f, 0.f, 0.f};

  // bias prefetch (held in 4 VGPRs through the loop)
  float bv[4];
#pragma unroll
  for (int tn = 0; tn < 4; tn++) bv[tn] = bias[bn + wn * 64 + tn * 16 + ln];

  const int nkt = K >> 5;              // 32 (K=1024) or 128 (K=4096)

  // ---- prologue: stage kts 0,1,2; confirm kt0
  STAGE_A(0, 0);  STAGE_B(0, 0);
  STAGE_A(1, 32); STAGE_B(1, 32);
  STAGE_A(2, 64); STAGE_B(2, 64);
  asm volatile("s_waitcnt vmcnt(8)");
  __builtin_amdgcn_s_barrier();

#define MFROW(T, AF) \
    acc[T][0] = MFMA16(AF, bf0, acc[T][0], 0, 0, 0); \
    acc[T][1] = MFMA16(AF, bf1, acc[T][1], 0, 0, 0); \
    acc[T][2] = MFMA16(AF, bf2, acc[T][2], 0, 0, 0); \
    acc[T][3] = MFMA16(AF, bf3, acc[T][3], 0, 0, 0);

  // One K-tile: single scheduling region. STG/VMS are compile-time-selected.
#define KT(B_, KST, STG, VMS) { \
    if (STG) { STAGE_A((((B_) + 3) & 3), (KST)); STAGE_B((((B_) + 3) & 3), (KST)); } \
    const bf16* _pa = lA + (B_) * 16384 + raw; \
    const bf16* _pb = lA + (B_) * 16384 + rbw; \
    bf16x8 af0 = *(const bf16x8*)(_pa); \
    bf16x8 af1 = *(const bf16x8*)(_pa + 512); \
    bf16x8 af2 = *(const bf16x8*)(_pa + 1024); \
    bf16x8 af3 = *(const bf16x8*)(_pa + 1536); \
    bf16x8 af4 = *(const bf16x8*)(_pa + 2048); \
    bf16x8 af5 = *(const bf16x8*)(_pa + 2560); \
    bf16x8 af6 = *(const bf16x8*)(_pa + 3072); \
    bf16x8 af7 = *(const bf16x8*)(_pa + 3584); \
    bf16x8 bf0 = *(const bf16x8*)(_pb); \
    bf16x8 bf1 = *(const bf16x8*)(_pb + 512); \
    bf16x8 bf2 = *(const bf16x8*)(_pb + 1024); \
    bf16x8 bf3 = *(const bf16x8*)(_pb + 1536); \
    __builtin_amdgcn_s_setprio(1); \
    MFROW(0, af0) MFROW(1, af1) MFROW(2, af2) MFROW(3, af3) \
    MFROW(4, af4) MFROW(5, af5) MFROW(6, af6) MFROW(7, af7) \
    __builtin_amdgcn_s_setprio(0); \
    VMS; \
    __builtin_amdgcn_s_barrier(); }

#define V8 asm volatile("s_waitcnt vmcnt(8)")
#define V4 asm volatile("s_waitcnt vmcnt(4)")
#define V0 asm volatile("s_waitcnt vmcnt(0)")
#define VN (void)0

  // ---- main loop: kts 0 .. nkt-5, branch-free body
  for (int mm = 0; mm < nkt - 4; mm += 4) {
    const int kst = (mm + 3) * 32;
    KT(0, kst,       true, V8)
    KT(1, kst + 32,  true, V8)
    KT(2, kst + 64,  true, V8)
    KT(3, kst + 96,  true, V8)
  }
  // ---- tail: kts nkt-4 .. nkt-1 (bufs 0..3)
  KT(0, (nkt - 1) * 32, true,  V8)   // stages last kt
  KT(1, 0,              false, V4)
  KT(2, 0,              false, V0)
  KT(3, 0,              false, VN)
#undef KT
#undef MFROW
#undef V8
#undef V4
#undef V0
#undef VN
#undef STAGE_A
#undef STAGE_B

  // ---- epilogue: 8 passes over tm. C/D layout col=ln, row=q*4+reg.
  bf16* eb = (bf16*)smem;
  const int lrow = tid >> 4;          // 0..31
  const int cb   = (tid & 15) * 16;   // 0..240
#pragma unroll
  for (int tm = 0; tm < 8; tm++) {
    __syncthreads();
#pragma unroll
    for (int tn = 0; tn < 4; tn++)
#pragma unroll
      for (int i = 0; i < 4; i++)
        eb[(wm * 16 + q * 4 + i) * 264 + wn * 64 + tn * 16 + ln] =
            (bf16)(acc[tm][tn][i] + bv[tn]);
    __syncthreads();
    int gR = bm + (lrow >> 4) * 128 + tm * 16 + (lrow & 15);
    size_t rowoff = (size_t)gR * N + bn + cb;
    bf16x8 v0 = *(const bf16x8*)&eb[lrow * 264 + cb];
    bf16x8 v1 = *(const bf16x8*)&eb[lrow * 264 + cb + 8];
    if (RES) {
      bf16x8 r0 = *(const bf16x8*)(resid + rowoff);
      bf16x8 r1 = *(const bf16x8*)(resid + rowoff + 8);
#pragma unroll
      for (int u = 0; u < 8; u++) {
        v0[u] = (bf16)((float)v0[u] + (float)r0[u]);
        v1[u] = (bf16)((float)v1[u] + (float)r1[u]);
      }
    }
    if (GELU) {
      // tanh-form GELU, NaN-safe: a - a/(1+exp2(2.3022082*a*(1+0.044715a^2)))
#pragma unroll
      for (int u = 0; u < 8; u++) {
        float a = (float)v0[u], c = (float)v1[u];
        float ea = __builtin_amdgcn_exp2f(2.3022082f * a * (1.0f + 0.044715f * a * a));
        float ec = __builtin_amdgcn_exp2f(2.3022082f * c * (1.0f + 0.044715f * c * c));
        v0[u] = (bf16)(a - a * __builtin_amdgcn_rcpf(ea + 1.0f));
        v1[u] = (bf16)(c - c * __builtin_amdgcn_rcpf(ec + 1.0f));
      }
    }
    *(bf16x8*)(C + rowoff)     = v0;
    *(bf16x8*)(C + rowoff + 8) = v1;
  }
}

// ---------------- 3. windowed attention: bf16 LDS, b128 reads ----------------
__global__ __launch_bounds__(256) void attn_kernel(
    const bf16* __restrict__ qkv, bf16* __restrict__ o)
{
  __shared__ bf16 sq[16][136], sk[16][136], sv[16][136];  // pad 8 elems = 16 B
  __shared__ float ss[16][17];

  int wid = blockIdx.x;
  int h   = wid & 7;
  int win = wid >> 3;
  int tb  = win * 16;     // token base row

  int t  = threadIdx.x;
  int r  = t >> 4;        // 0..15
  int c8 = (t & 15) * 8;  // 0..120

  const bf16* base = qkv + (size_t)(tb + r) * 3072 + c8;
  *(bf16x8*)&sq[r][c8] = *(const bf16x8*)(base + h * 128);
  *(bf16x8*)&sk[r][c8] = *(const bf16x8*)(base + 1024 + h * 128);
  *(bf16x8*)&sv[r][c8] = *(const bf16x8*)(base + 2048 + h * 128);
  __syncthreads();

  {  // scores: thread (i,j) does 128-dot via 16x2 b128 reads
    int i = t >> 4, jj = t & 15;
    float s = 0.f;
#pragma unroll
    for (int d8 = 0; d8 < 16; d8++) {
      bf16x8 qa = *(const bf16x8*)&sq[i][d8 * 8];
      bf16x8 kb = *(const bf16x8*)&sk[jj][d8 * 8];
#pragma unroll
      for (int u = 0; u < 8; u++) s += (float)qa[u] * (float)kb[u];
    }
    ss[i][jj] = s * 0.08838834764831845f;   // 1/sqrt(128)
  }
  __syncthreads();

  if (t < 16) {  // softmax, one thread per row
    float m = -1e30f;
    for (int jj = 0; jj < 16; jj++) m = fmaxf(m, ss[t][jj]);
    float sum = 0.f;
    for (int jj = 0; jj < 16; jj++) { float e = expf(ss[t][jj] - m); ss[t][jj] = e; sum += e; }
    float inv = 1.0f / sum;
    for (int jj = 0; jj < 16; jj++) ss[t][jj] *= inv;
  }
  __syncthreads();

  {  // o = attn @ v : thread does 8 output elems; 16 b128 reads
    int i = t >> 4; int d0 = (t & 15) * 8;
    float acc[8] = {0, 0, 0, 0, 0, 0, 0, 0};
#pragma unroll
    for (int jj = 0; jj < 16; jj++) {
      float a = ss[i][jj];
      bf16x8 vv8 = *(const bf16x8*)&sv[jj][d0];
#pragma unroll
      for (int u = 0; u < 8; u++) acc[u] += a * (float)vv8[u];
    }
    bf16* op = o + (size_t)(tb + i) * 1024 + h * 128 + d0;
    bf16x8 ov;
#pragma unroll
    for (int u = 0; u < 8; u++) ov[u] = (bf16)acc[u];
    *(bf16x8*)op = ov;
  }
}

// ---------------- 4. LayerNorm (row = 1024, biased var), templated output ------
template<typename OUT_T>
__global__ __launch_bounds__(256) void ln_kernel(
    const bf16* __restrict__ x, const float* __restrict__ g,
    const float* __restrict__ b, OUT_T* __restrict__ y)
{
  __shared__ float red[8];
  int row = blockIdx.x;
  int t   = threadIdx.x;
  int lane = t & 63, wave = t >> 6;

  bf16x4 v4 = *(const bf16x4*)(x + (size_t)row * 1024 + t * 4);
  float v[4];
  float s = 0.f, sq = 0.f;
#pragma unroll
  for (int u = 0; u < 4; u++) {
    v[u] = (float)v4[u];
    s += v[u];
    sq += v[u] * v[u];
  }
  for (int off = 32; off > 0; off >>= 1) {
    s  += __shfl_down(s, off);
    sq += __shfl_down(sq, off);
  }
  if (lane == 0) { red[wave * 2] = s; red[wave * 2 + 1] = sq; }
  __syncthreads();
  float st = red[0] + red[2] + red[4] + red[6];
  float qt = red[1] + red[3] + red[5] + red[7];
  float mean = st * (1.0f / 1024.0f);
  float var  = qt * (1.0f / 1024.0f) - mean * mean;
  float inv  = rsqrtf(var + 1e-5f);
  int c = t * 4;
  OUT_T* yr = y + (size_t)row * 1024 + c;
#pragma unroll
  for (int u = 0; u < 4; u++)
    yr[u] = (OUT_T)((v[u] - mean) * inv * g[c + u] + b[c + u]);
}

// ---------------- launch ----------------
extern "C" void kernel_launch(void* const* d_in, const int* in_sizes, int n_in,
                              void* d_out, int out_size, void* d_ws, size_t ws_size,
                              hipStream_t stream) {
  const float* ff    = (const float*)d_in[0];
  const int*   idx   = (const int*)d_in[1];
  const float* w_qkv = (const float*)d_in[2];
  const float* b_qkv = (const float*)d_in[3];
  const float* w_out = (const float*)d_in[4];
  const float* b_out = (const float*)d_in[5];
  const float* w1    = (const float*)d_in[6];
  const float* b1    = (const float*)d_in[7];
  const float* w2    = (const float*)d_in[8];
  const float* b2    = (const float*)d_in[9];
  const float* g1    = (const float*)d_in[10];
  const float* be1   = (const float*)d_in[11];
  const float* g2    = (const float*)d_in[12];
  const float* be2   = (const float*)d_in[13];
  float* out = (float*)d_out;

  // opt-in to 128 KiB dynamic LDS (once)
  static bool attrs_done = false;
  if (!attrs_done) {
    attrs_done = true;
    hipFuncSetAttribute(reinterpret_cast<const void*>(&gemm8<false, false>),
                        hipFuncAttributeMaxDynamicSharedMemorySize, 131072);
    hipFuncSetAttribute(reinterpret_cast<const void*>(&gemm8<false, true>),
                        hipFuncAttributeMaxDynamicSharedMemorySize, 131072);
    hipFuncSetAttribute(reinterpret_cast<const void*>(&gemm8<true, false>),
                        hipFuncAttributeMaxDynamicSharedMemorySize, 131072);
  }

  char* p = (char*)d_ws;
  bf16* x_bf = (bf16*)p;  p += (size_t)ROWS * 1024 * 2;   // 32MB
  bf16* big  = (bf16*)p;  p += (size_t)ROWS * 4096 * 2;   // 128MB: qkv|o, later gelu acts
  bf16* s_bf = (bf16*)p;  p += (size_t)ROWS * 1024 * 2;   // 32MB
  bf16* h_bf = (bf16*)p;  p += (size_t)ROWS * 1024 * 2;   // 32MB
  bf16* wqb  = (bf16*)p;  p += (size_t)3072 * 1024 * 2;
  bf16* wob  = (bf16*)p;  p += (size_t)1024 * 1024 * 2;
  bf16* w1b  = (bf16*)p;  p += (size_t)4096 * 1024 * 2;
  bf16* w2b  = (bf16*)p;  p += (size_t)1024 * 4096 * 2;
  bf16* o_bf = big + (size_t)ROWS * 3072;   // lives in big's tail during attention
  bf16* g_bf = big;                          // reuses big after attention done

  // all four weight casts in one launch (12.58M elems / 8 / 256 = 6144 blocks)
  cast4_kernel<<<6144, 256, 0, stream>>>(
      w_qkv, wqb, 3072 * 1024,
      w_out, wob, 1024 * 1024,
      w1,    w1b, 4096 * 1024,
      w2,    w2b, 1024 * 4096);

  pe_add_kernel<<<ROWS * 512 / 256, 256, 0, stream>>>(ff, idx, x_bf);

  // grids: (M/256) * (N/256); all % 8 == 0 for the XCD swizzle
  gemm8<false, false><<<64 * 12, 512, 131072, stream>>>(
      x_bf, wqb, b_qkv, nullptr, big, ROWS, 3072, 1024);
  attn_kernel<<<(ROWS / 16) * 8, 256, 0, stream>>>(big, o_bf);
  gemm8<false, true><<<64 * 4, 512, 131072, stream>>>(
      o_bf, wob, b_out, x_bf, s_bf, ROWS, 1024, 1024);
  ln_kernel<bf16><<<ROWS, 256, 0, stream>>>(s_bf, g1, be1, h_bf);
  gemm8<true, false><<<64 * 16, 512, 131072, stream>>>(
      h_bf, w1b, b1, nullptr, big, ROWS, 4096, 1024);
  gemm8<false, true><<<64 * 4, 512, 131072, stream>>>(
      g_bf, w2b, b2, h_bf, s_bf, ROWS, 1024, 4096);
  ln_kernel<float><<<ROWS, 256, 0, stream>>>(s_bf, g2, be2, out);
}